// Round 13
// baseline (202.087 us; speedup 1.0000x reference)
//
#include <hip/hip_runtime.h>

#define Bn 2
#define Ln 4096
#define Hn 8
#define Dn 64
#define NMEGA 32           // 128-key mega-tiles
#define BH_STRIDE 262144   // halves per bh in kp/vp

typedef float    f32x4  __attribute__((ext_vector_type(4)));
typedef float    f32x16 __attribute__((ext_vector_type(16)));
typedef _Float16 f16x2  __attribute__((ext_vector_type(2)));
typedef _Float16 f16x8  __attribute__((ext_vector_type(8)));
typedef unsigned int u32;
typedef u32 u32x2 __attribute__((ext_vector_type(2)));
typedef u32 u32x4 __attribute__((ext_vector_type(4)));

static __device__ __forceinline__ u32 pkf16(float a, float b){
    auto h = __builtin_amdgcn_cvt_pkrtz(a, b);   // v_cvt_pkrtz_f16_f32
    return __builtin_bit_cast(u32, h);
}

static __device__ __forceinline__ u32x2 swp(u32 a, u32 b){
    auto r = __builtin_amdgcn_permlane32_swap(a, b, false, false);
    return __builtin_bit_cast(u32x2, r);
}

// ---- fused prep, STREAMING (R11, verified): no LDS, no barrier ----
// Block (t2, bh) = one 32-key g-group. Wave w emits K unit cc=w, V unit j=w.
// Output layout/values bit-identical to the original kvprep (RTN casts).
__global__ __launch_bounds__(256)
void kvprep(const float* __restrict__ Kg, const float* __restrict__ Vg,
            _Float16* __restrict__ kp, _Float16* __restrict__ vp){
    const int t2 = blockIdx.x, bh = blockIdx.y, b = bh>>3, h = bh&7;
    const int tid = threadIdx.x;
    const int w = tid >> 6, lane = tid & 63;
    const int l31 = lane & 31, hi = lane >> 5;
    const int t = t2 >> 1, g = t2 & 1;

    // ---- K unit cc=w ----
    {
        const float* ks = Kg + (((size_t)b*Ln + t2*32 + l31)*Hn + h)*Dn + w*16 + hi*8;
        float4 a  = *(const float4*)ks;
        float4 c4 = *(const float4*)(ks + 4);
        f16x8 o;
        o[0]=(_Float16)a.x;  o[1]=(_Float16)a.y;  o[2]=(_Float16)a.z;  o[3]=(_Float16)a.w;
        o[4]=(_Float16)c4.x; o[5]=(_Float16)c4.y; o[6]=(_Float16)c4.z; o[7]=(_Float16)c4.w;
        *(f16x8*)(kp + (size_t)bh*BH_STRIDE + (size_t)t*4096
                     + (size_t)(g*4 + w)*512 + (size_t)lane*8) = o;
    }

    // ---- V unit j=w (kh=w>>1, dt=w&1) ----
    {
        const int kh = w >> 1, dt = w & 1;
        const float* vs = Vg + (((size_t)b*Ln + t2*32 + kh*16 + hi*8)*Hn + h)*Dn
                        + dt*32 + l31;
        f16x8 o;
#pragma unroll
        for(int j=0;j<8;++j) o[j] = (_Float16)vs[(size_t)j*Hn*Dn];
        *(f16x8*)(vp + (size_t)bh*BH_STRIDE + (size_t)t*4096
                     + (size_t)(g*4 + w)*512 + (size_t)lane*8) = o;
    }
}

// QK: 4-deep 32x32x16 chain from zero accumulator
static __device__ __forceinline__ f32x16 qk4(const f16x8 (&kf)[4], const f16x8 (&qf)[4]){
    f32x16 s;
#pragma unroll
    for(int r=0;r<16;++r) s[r]=0.f;
    s = __builtin_amdgcn_mfma_f32_32x32x16_f16(kf[0], qf[0], s, 0,0,0);
    s = __builtin_amdgcn_mfma_f32_32x32x16_f16(kf[1], qf[1], s, 0,0,0);
    s = __builtin_amdgcn_mfma_f32_32x32x16_f16(kf[2], qf[2], s, 0,0,0);
    s = __builtin_amdgcn_mfma_f32_32x32x16_f16(kf[3], qf[3], s, 0,0,0);
    return s;
}

// finish: exp2 -> pack (cvt_pkrtz + permlane32_swap) -> consistent-l via fdot2
// -> PV accumulate. Identical op set/order to R8/R10/R11 (passing numerics).
static __device__ __forceinline__ void finish_pv(const f32x16& S, float& lac,
                                                 f32x16& o0, f32x16& o1,
                                                 const f16x8 (&vf)[4]){
    f32x16 p;
#pragma unroll
    for(int r=0;r<16;++r) p[r] = __builtin_amdgcn_exp2f(S[r]);
    u32 A0 = pkf16(p[0],p[1]),   A1 = pkf16(p[2],p[3]);
    u32 B0 = pkf16(p[4],p[5]),   B1 = pkf16(p[6],p[7]);
    u32 C0 = pkf16(p[8],p[9]),   C1 = pkf16(p[10],p[11]);
    u32 D0 = pkf16(p[12],p[13]), D1 = pkf16(p[14],p[15]);
    u32x2 r0 = swp(A0,B0), r1 = swp(A1,B1);
    u32x2 r2 = swp(C0,D0), r3 = swp(C1,D1);
    u32x4 w0 = {r0.x, r1.x, r0.y, r1.y};   // keys [0,16) of this 32-key group
    u32x4 w1 = {r2.x, r3.x, r2.y, r3.y};   // keys [16,32)
    f16x8 pa0 = __builtin_bit_cast(f16x8, w0);
    f16x8 pa1 = __builtin_bit_cast(f16x8, w1);
    const f16x2 ones = {(_Float16)1.0f, (_Float16)1.0f};
#pragma unroll
    for(int j=0;j<4;++j){
        f16x2 c0 = {pa0[2*j], pa0[2*j+1]};
        f16x2 c1 = {pa1[2*j], pa1[2*j+1]};
        lac = __builtin_amdgcn_fdot2(c0, ones, lac, false);
        lac = __builtin_amdgcn_fdot2(c1, ones, lac, false);
    }
    // vf[j], j = kh*2+dt
    o0 = __builtin_amdgcn_mfma_f32_32x32x16_f16(pa0, vf[0], o0, 0,0,0);
    o0 = __builtin_amdgcn_mfma_f32_32x32x16_f16(pa1, vf[2], o0, 0,0,0);
    o1 = __builtin_amdgcn_mfma_f32_32x32x16_f16(pa0, vf[1], o1, 0,0,0);
    o1 = __builtin_amdgcn_mfma_f32_32x32x16_f16(pa1, vf[3], o1, 0,0,0);
}

// load 4 fragment registers (b128 each) from fragment-major global
static __device__ __forceinline__ void ld4(f16x8 (&dst)[4], const char* base, int off){
#pragma unroll
    for(int i=0;i<4;++i) dst[i] = *(const f16x8*)(base + ((off+i)<<10));
}

// ---- main kernel: R8's no-LDS free-run at HALF per-wave work, 2x grid ----
// Occupancy ledger (R2..R12): launch_bounds cap = 256/arg (block-size-
// independent); 512-thread blocks make the allocator over-squeeze (R2:64,
// R10:56) -> use 256-thread blocks only. R8 (VGPR 112, 35 KB LDS) already
// PERMITTED 4 blocks/CU; its 512-block grid supplied only 2. Fix: block =
// 4 waves over 64 queries (kh2=wv&1, qh=wv>>1 in [0,2)); grid (16,64) =
// 1024 blocks -> 4 blocks/CU -> 4 waves/SIMD free-running. Per-wave state
// halves (o 32 + qf 16 regs -> ~100 natural < 128 cap). Per-wave compute
// order == R10 (passed; per-query numerics identical to R8).
// L2: 2 bh x 2 MB per XCD resident; sentinel = FETCH_SIZE stays ~16.4 MB.
__global__ __launch_bounds__(256,2)
void attn_fwd(const float* __restrict__ Qg, float* __restrict__ Og,
              const _Float16* __restrict__ kp, const _Float16* __restrict__ vp){
    __shared__ __align__(16) float xo[2*32*64 + 64];   // epilogue combine (16.6 KB)

    const int tid  = threadIdx.x;
    const int lane = tid & 63, wv = tid >> 6;
    const int kh2 = wv & 1, qh = wv >> 1;          // qh in [0,2)
    const int l31 = lane & 31, hi = lane >> 5;
    const int bh = blockIdx.x, b = bh>>3, h = bh&7;
    const int q0 = blockIdx.y*64 + qh*32;

    const float c = 0.125f * 1.4426950408889634f;    // scale * log2(e)

    // Q B-frags: lane holds query=l31, d = cc*16 + hi*8 + j
    f16x8 qf[4];
    {
        const float* qrow = Qg + (((size_t)b*Ln + q0 + l31)*Hn + h)*Dn;
#pragma unroll
        for(int cc=0;cc<4;++cc){
            const float* p4 = qrow + cc*16 + hi*8;
            float4 x = *(const float4*)p4;
            float4 y = *(const float4*)(p4+4);
            f16x8 f;
            f[0]=(_Float16)(x.x*c); f[1]=(_Float16)(x.y*c);
            f[2]=(_Float16)(x.z*c); f[3]=(_Float16)(x.w*c);
            f[4]=(_Float16)(y.x*c); f[5]=(_Float16)(y.y*c);
            f[6]=(_Float16)(y.z*c); f[7]=(_Float16)(y.w*c);
            qf[cc]=f;
        }
    }

    f32x16 o0, o1;
    float lac = 0.f;
#pragma unroll
    for(int r=0;r<16;++r){ o0[r]=0.f; o1[r]=0.f; }

    // per-lane global base of this wave's 64-key half within each mega-tile:
    // mega-tile stride 16 KB; within it: kh2 half (8 KB), unit (1 KB), lane*16.
    const char* kgc = (const char*)(kp + (size_t)bh*BH_STRIDE) + kh2*8192 + lane*16;
    const char* vgc = (const char*)(vp + (size_t)bh*BH_STRIDE) + kh2*8192 + lane*16;

    for(int T=0; T<NMEGA; ++T){
        const char* Kb = kgc + (size_t)T*16384;
        const char* Vb = vgc + (size_t)T*16384;

        f16x8 kf0[4], vf0[4];
        ld4(kf0, Kb, 0); ld4(vf0, Vb, 0);
        f32x16 S0 = qk4(kf0, qf);             // g=0

        f16x8 kf1[4], vf1[4];
        ld4(kf1, Kb, 4); ld4(vf1, Vb, 4);
        finish_pv(S0, lac, o0, o1, vf0);

        f32x16 S1 = qk4(kf1, qf);             // g=1
        finish_pv(S1, lac, o0, o1, vf1);
    }

    // ---- reduce l within wave: lanes l and l+32 cover complementary key slots ----
    float lred = lac + __shfl_xor(lac, 32, 64);

    // ---- epilogue: combine kh2 halves through LDS ----
    float* xl = xo + 2*32*64;
    if(kh2){
#pragma unroll
        for(int r=0;r<16;++r){
            int qr = (r&3) + 8*(r>>2) + 4*hi;
            xo[(qh*32 + qr)*64 +  0 + l31] = o0[r];
            xo[(qh*32 + qr)*64 + 32 + l31] = o1[r];
        }
        if(hi==0) xl[qh*32 + l31] = lred;
    }
    __syncthreads();
    if(!kh2){
        float inv = 1.0f/(lred + xl[qh*32 + l31]);
        float* ob = Og + (((size_t)b*Ln + q0)*Hn + h)*Dn;
#pragma unroll
        for(int r=0;r<16;++r){
            int qr = (r&3) + 8*(r>>2) + 4*hi;
            float invr = __shfl(inv, qr, 64);   // lane qr holds query qr's inv
            float v0 = o0[r] + xo[(qh*32 + qr)*64 +  0 + l31];
            float v1 = o1[r] + xo[(qh*32 + qr)*64 + 32 + l31];
            ob[(size_t)qr*Hn*Dn +  0 + l31] = v0*invr;
            ob[(size_t)qr*Hn*Dn + 32 + l31] = v1*invr;
        }
    }
}

extern "C" void kernel_launch(void* const* d_in, const int* in_sizes, int n_in,
                              void* d_out, int out_size, void* d_ws, size_t ws_size,
                              hipStream_t stream) {
    const float* Q = (const float*)d_in[0];
    const float* K = (const float*)d_in[1];
    const float* V = (const float*)d_in[2];
    float* O = (float*)d_out;

    _Float16* kp = (_Float16*)d_ws;                        // 8 MB
    _Float16* vp = (_Float16*)((char*)d_ws + (8u<<20));    // 8 MB

    kvprep<<<dim3(128, 16), dim3(256), 0, stream>>>(K, V, kp, vp);
    attn_fwd<<<dim3(16, 64), dim3(256), 0, stream>>>(Q, O, kp, vp);
}

// Round 14
// 177.851 us; speedup vs baseline: 1.1363x; 1.1363x over previous
//
#include <hip/hip_runtime.h>

#define Bn 2
#define Ln 4096
#define Hn 8
#define Dn 64
#define NMEGA 32           // 128-key mega-tiles
#define BH_STRIDE 262144   // halves per bh in kp/vp

typedef float    f32x4  __attribute__((ext_vector_type(4)));
typedef float    f32x16 __attribute__((ext_vector_type(16)));
typedef _Float16 f16x2  __attribute__((ext_vector_type(2)));
typedef _Float16 f16x8  __attribute__((ext_vector_type(8)));
typedef unsigned int u32;
typedef u32 u32x2 __attribute__((ext_vector_type(2)));
typedef u32 u32x4 __attribute__((ext_vector_type(4)));

static __device__ __forceinline__ u32 pkf16(float a, float b){
    auto h = __builtin_amdgcn_cvt_pkrtz(a, b);   // v_cvt_pkrtz_f16_f32
    return __builtin_bit_cast(u32, h);
}

static __device__ __forceinline__ u32x2 swp(u32 a, u32 b){
    auto r = __builtin_amdgcn_permlane32_swap(a, b, false, false);
    return __builtin_bit_cast(u32x2, r);
}

// ---- fused prep, STREAMING (R11, verified): no LDS, no barrier ----
// Block (t2, bh) = one 32-key g-group. Wave w emits K unit cc=w, V unit j=w.
// Output layout/values bit-identical to the original kvprep (RTN casts).
__global__ __launch_bounds__(256)
void kvprep(const float* __restrict__ Kg, const float* __restrict__ Vg,
            _Float16* __restrict__ kp, _Float16* __restrict__ vp){
    const int t2 = blockIdx.x, bh = blockIdx.y, b = bh>>3, h = bh&7;
    const int tid = threadIdx.x;
    const int w = tid >> 6, lane = tid & 63;
    const int l31 = lane & 31, hi = lane >> 5;
    const int t = t2 >> 1, g = t2 & 1;

    // ---- K unit cc=w ----
    {
        const float* ks = Kg + (((size_t)b*Ln + t2*32 + l31)*Hn + h)*Dn + w*16 + hi*8;
        float4 a  = *(const float4*)ks;
        float4 c4 = *(const float4*)(ks + 4);
        f16x8 o;
        o[0]=(_Float16)a.x;  o[1]=(_Float16)a.y;  o[2]=(_Float16)a.z;  o[3]=(_Float16)a.w;
        o[4]=(_Float16)c4.x; o[5]=(_Float16)c4.y; o[6]=(_Float16)c4.z; o[7]=(_Float16)c4.w;
        *(f16x8*)(kp + (size_t)bh*BH_STRIDE + (size_t)t*4096
                     + (size_t)(g*4 + w)*512 + (size_t)lane*8) = o;
    }

    // ---- V unit j=w (kh=w>>1, dt=w&1) ----
    {
        const int kh = w >> 1, dt = w & 1;
        const float* vs = Vg + (((size_t)b*Ln + t2*32 + kh*16 + hi*8)*Hn + h)*Dn
                        + dt*32 + l31;
        f16x8 o;
#pragma unroll
        for(int j=0;j<8;++j) o[j] = (_Float16)vs[(size_t)j*Hn*Dn];
        *(f16x8*)(vp + (size_t)bh*BH_STRIDE + (size_t)t*4096
                     + (size_t)(g*4 + w)*512 + (size_t)lane*8) = o;
    }
}

// QK: 4-deep 32x32x16 chain from zero accumulator
static __device__ __forceinline__ f32x16 qk4(const f16x8 (&kf)[4], const f16x8 (&qf)[4]){
    f32x16 s;
#pragma unroll
    for(int r=0;r<16;++r) s[r]=0.f;
    s = __builtin_amdgcn_mfma_f32_32x32x16_f16(kf[0], qf[0], s, 0,0,0);
    s = __builtin_amdgcn_mfma_f32_32x32x16_f16(kf[1], qf[1], s, 0,0,0);
    s = __builtin_amdgcn_mfma_f32_32x32x16_f16(kf[2], qf[2], s, 0,0,0);
    s = __builtin_amdgcn_mfma_f32_32x32x16_f16(kf[3], qf[3], s, 0,0,0);
    return s;
}

// finish: exp2 -> pack (cvt_pkrtz + permlane32_swap) -> consistent-l via fdot2
// -> PV accumulate. Identical op set/order to R8/R10/R11/R13 (passing numerics).
static __device__ __forceinline__ void finish_pv(const f32x16& S, float& lac,
                                                 f32x16& o0, f32x16& o1,
                                                 const f16x8 (&vf)[4]){
    f32x16 p;
#pragma unroll
    for(int r=0;r<16;++r) p[r] = __builtin_amdgcn_exp2f(S[r]);
    u32 A0 = pkf16(p[0],p[1]),   A1 = pkf16(p[2],p[3]);
    u32 B0 = pkf16(p[4],p[5]),   B1 = pkf16(p[6],p[7]);
    u32 C0 = pkf16(p[8],p[9]),   C1 = pkf16(p[10],p[11]);
    u32 D0 = pkf16(p[12],p[13]), D1 = pkf16(p[14],p[15]);
    u32x2 r0 = swp(A0,B0), r1 = swp(A1,B1);
    u32x2 r2 = swp(C0,D0), r3 = swp(C1,D1);
    u32x4 w0 = {r0.x, r1.x, r0.y, r1.y};   // keys [0,16) of this 32-key group
    u32x4 w1 = {r2.x, r3.x, r2.y, r3.y};   // keys [16,32)
    f16x8 pa0 = __builtin_bit_cast(f16x8, w0);
    f16x8 pa1 = __builtin_bit_cast(f16x8, w1);
    const f16x2 ones = {(_Float16)1.0f, (_Float16)1.0f};
#pragma unroll
    for(int j=0;j<4;++j){
        f16x2 c0 = {pa0[2*j], pa0[2*j+1]};
        f16x2 c1 = {pa1[2*j], pa1[2*j+1]};
        lac = __builtin_amdgcn_fdot2(c0, ones, lac, false);
        lac = __builtin_amdgcn_fdot2(c1, ones, lac, false);
    }
    // vf[j], j = kh*2+dt
    o0 = __builtin_amdgcn_mfma_f32_32x32x16_f16(pa0, vf[0], o0, 0,0,0);
    o0 = __builtin_amdgcn_mfma_f32_32x32x16_f16(pa1, vf[2], o0, 0,0,0);
    o1 = __builtin_amdgcn_mfma_f32_32x32x16_f16(pa0, vf[1], o1, 0,0,0);
    o1 = __builtin_amdgcn_mfma_f32_32x32x16_f16(pa1, vf[3], o1, 0,0,0);
}

// load 4 fragment registers (b128 each) from fragment-major global
static __device__ __forceinline__ void ld4(f16x8 (&dst)[4], const char* base, int off){
#pragma unroll
    for(int i=0;i<4;++i) dst[i] = *(const f16x8*)(base + ((off+i)<<10));
}

// ---- main kernel: R13 geometry + LDS-TIER PIN + explicit in-tile ILP ----
// ALLOCATOR RULE (R2..R13 ledger): VGPR cap = min(256/launch_bounds_arg,
// tier implied by LDS-allowed occupancy). R13's 16.9 KB LDS let the
// compiler target 8 waves/SIMD -> squeezed to 56 VGPR -> every ld4 sunk to
// its consumer, L2 latency fully exposed, waves 2.9x slower (122 us).
// FIX: pad LDS to 36 KB -> LDS itself caps at 4 blocks/CU = 4 waves/SIMD
// -> compiler targets the 128-reg tier (R8 measured 112 at 35 KB).
// Tile body: all 16 fragment loads issued UP FRONT (one waitcnt batch),
// then both independent QK chains back-to-back, then both finishes.
// Accumulation order into lac/o0/o1 bit-identical to R13 (passed).
// Grid (16,64) = 1024 blocks -> 4 blocks/CU -> 4 waves/SIMD free-running.
__global__ __launch_bounds__(256,2)
void attn_fwd(const float* __restrict__ Qg, float* __restrict__ Og,
              const _Float16* __restrict__ kp, const _Float16* __restrict__ vp){
    // 36 KB: epilogue uses first 2*32*64+64 floats; rest is an occupancy
    // governor (forces the 4-blocks/CU register tier).
    __shared__ __align__(16) float xo[9216];

    const int tid  = threadIdx.x;
    const int lane = tid & 63, wv = tid >> 6;
    const int kh2 = wv & 1, qh = wv >> 1;          // qh in [0,2)
    const int l31 = lane & 31, hi = lane >> 5;
    const int bh = blockIdx.x, b = bh>>3, h = bh&7;
    const int q0 = blockIdx.y*64 + qh*32;

    const float c = 0.125f * 1.4426950408889634f;    // scale * log2(e)

    // Q B-frags: lane holds query=l31, d = cc*16 + hi*8 + j
    f16x8 qf[4];
    {
        const float* qrow = Qg + (((size_t)b*Ln + q0 + l31)*Hn + h)*Dn;
#pragma unroll
        for(int cc=0;cc<4;++cc){
            const float* p4 = qrow + cc*16 + hi*8;
            float4 x = *(const float4*)p4;
            float4 y = *(const float4*)(p4+4);
            f16x8 f;
            f[0]=(_Float16)(x.x*c); f[1]=(_Float16)(x.y*c);
            f[2]=(_Float16)(x.z*c); f[3]=(_Float16)(x.w*c);
            f[4]=(_Float16)(y.x*c); f[5]=(_Float16)(y.y*c);
            f[6]=(_Float16)(y.z*c); f[7]=(_Float16)(y.w*c);
            qf[cc]=f;
        }
    }

    f32x16 o0, o1;
    float lac = 0.f;
#pragma unroll
    for(int r=0;r<16;++r){ o0[r]=0.f; o1[r]=0.f; }

    // per-lane global base of this wave's 64-key half within each mega-tile:
    // mega-tile stride 16 KB; within it: kh2 half (8 KB), unit (1 KB), lane*16.
    const char* kgc = (const char*)(kp + (size_t)bh*BH_STRIDE) + kh2*8192 + lane*16;
    const char* vgc = (const char*)(vp + (size_t)bh*BH_STRIDE) + kh2*8192 + lane*16;

    for(int T=0; T<NMEGA; ++T){
        const char* Kb = kgc + (size_t)T*16384;
        const char* Vb = vgc + (size_t)T*16384;

        // batch all 16 fragment loads (32 VGPRs) -> single latency window
        f16x8 kf0[4], kf1[4], vf0[4], vf1[4];
        ld4(kf0, Kb, 0); ld4(kf1, Kb, 4);
        ld4(vf0, Vb, 0); ld4(vf1, Vb, 4);

        // two independent QK chains back-to-back (MFMA pipe stays fed)
        f32x16 S0 = qk4(kf0, qf);             // g=0
        f32x16 S1 = qk4(kf1, qf);             // g=1

        finish_pv(S0, lac, o0, o1, vf0);
        finish_pv(S1, lac, o0, o1, vf1);
    }

    // ---- reduce l within wave: lanes l and l+32 cover complementary key slots ----
    float lred = lac + __shfl_xor(lac, 32, 64);

    // ---- epilogue: combine kh2 halves through LDS ----
    float* xl = xo + 2*32*64;
    if(kh2){
#pragma unroll
        for(int r=0;r<16;++r){
            int qr = (r&3) + 8*(r>>2) + 4*hi;
            xo[(qh*32 + qr)*64 +  0 + l31] = o0[r];
            xo[(qh*32 + qr)*64 + 32 + l31] = o1[r];
        }
        if(hi==0) xl[qh*32 + l31] = lred;
    }
    __syncthreads();
    if(!kh2){
        float inv = 1.0f/(lred + xl[qh*32 + l31]);
        float* ob = Og + (((size_t)b*Ln + q0)*Hn + h)*Dn;
#pragma unroll
        for(int r=0;r<16;++r){
            int qr = (r&3) + 8*(r>>2) + 4*hi;
            float invr = __shfl(inv, qr, 64);   // lane qr holds query qr's inv
            float v0 = o0[r] + xo[(qh*32 + qr)*64 +  0 + l31];
            float v1 = o1[r] + xo[(qh*32 + qr)*64 + 32 + l31];
            ob[(size_t)qr*Hn*Dn +  0 + l31] = v0*invr;
            ob[(size_t)qr*Hn*Dn + 32 + l31] = v1*invr;
        }
    }
}

extern "C" void kernel_launch(void* const* d_in, const int* in_sizes, int n_in,
                              void* d_out, int out_size, void* d_ws, size_t ws_size,
                              hipStream_t stream) {
    const float* Q = (const float*)d_in[0];
    const float* K = (const float*)d_in[1];
    const float* V = (const float*)d_in[2];
    float* O = (float*)d_out;

    _Float16* kp = (_Float16*)d_ws;                        // 8 MB
    _Float16* vp = (_Float16*)((char*)d_ws + (8u<<20));    // 8 MB

    kvprep<<<dim3(128, 16), dim3(256), 0, stream>>>(K, V, kp, vp);
    attn_fwd<<<dim3(16, 64), dim3(256), 0, stream>>>(Q, O, kp, vp);
}

// Round 15
// 168.498 us; speedup vs baseline: 1.1993x; 1.0555x over previous
//
#include <hip/hip_runtime.h>

#define Bn 2
#define Ln 4096
#define Hn 8
#define Dn 64
#define NMEGA 32           // 128-key mega-tiles
#define BH_STRIDE 262144   // halves per bh in kp/vp

typedef float    f32x4  __attribute__((ext_vector_type(4)));
typedef float    f32x16 __attribute__((ext_vector_type(16)));
typedef _Float16 f16x2  __attribute__((ext_vector_type(2)));
typedef _Float16 f16x8  __attribute__((ext_vector_type(8)));
typedef unsigned int u32;
typedef u32 u32x2 __attribute__((ext_vector_type(2)));
typedef u32 u32x4 __attribute__((ext_vector_type(4)));

static __device__ __forceinline__ u32 pkf16(float a, float b){
    auto h = __builtin_amdgcn_cvt_pkrtz(a, b);   // v_cvt_pkrtz_f16_f32
    return __builtin_bit_cast(u32, h);
}

static __device__ __forceinline__ u32x2 swp(u32 a, u32 b){
    auto r = __builtin_amdgcn_permlane32_swap(a, b, false, false);
    return __builtin_bit_cast(u32x2, r);
}

// ---- fused prep, STREAMING (R11, verified): no LDS, no barrier ----
__global__ __launch_bounds__(256)
void kvprep(const float* __restrict__ Kg, const float* __restrict__ Vg,
            _Float16* __restrict__ kp, _Float16* __restrict__ vp){
    const int t2 = blockIdx.x, bh = blockIdx.y, b = bh>>3, h = bh&7;
    const int tid = threadIdx.x;
    const int w = tid >> 6, lane = tid & 63;
    const int l31 = lane & 31, hi = lane >> 5;
    const int t = t2 >> 1, g = t2 & 1;

    // ---- K unit cc=w ----
    {
        const float* ks = Kg + (((size_t)b*Ln + t2*32 + l31)*Hn + h)*Dn + w*16 + hi*8;
        float4 a  = *(const float4*)ks;
        float4 c4 = *(const float4*)(ks + 4);
        f16x8 o;
        o[0]=(_Float16)a.x;  o[1]=(_Float16)a.y;  o[2]=(_Float16)a.z;  o[3]=(_Float16)a.w;
        o[4]=(_Float16)c4.x; o[5]=(_Float16)c4.y; o[6]=(_Float16)c4.z; o[7]=(_Float16)c4.w;
        *(f16x8*)(kp + (size_t)bh*BH_STRIDE + (size_t)t*4096
                     + (size_t)(g*4 + w)*512 + (size_t)lane*8) = o;
    }

    // ---- V unit j=w (kh=w>>1, dt=w&1) ----
    {
        const int kh = w >> 1, dt = w & 1;
        const float* vs = Vg + (((size_t)b*Ln + t2*32 + kh*16 + hi*8)*Hn + h)*Dn
                        + dt*32 + l31;
        f16x8 o;
#pragma unroll
        for(int j=0;j<8;++j) o[j] = (_Float16)vs[(size_t)j*Hn*Dn];
        *(f16x8*)(vp + (size_t)bh*BH_STRIDE + (size_t)t*4096
                     + (size_t)(g*4 + w)*512 + (size_t)lane*8) = o;
    }
}

// QK: 4-deep 32x32x16 chain from zero accumulator
static __device__ __forceinline__ f32x16 qk4(const f16x8 (&kf)[4], const f16x8 (&qf)[4]){
    f32x16 s;
#pragma unroll
    for(int r=0;r<16;++r) s[r]=0.f;
    s = __builtin_amdgcn_mfma_f32_32x32x16_f16(kf[0], qf[0], s, 0,0,0);
    s = __builtin_amdgcn_mfma_f32_32x32x16_f16(kf[1], qf[1], s, 0,0,0);
    s = __builtin_amdgcn_mfma_f32_32x32x16_f16(kf[2], qf[2], s, 0,0,0);
    s = __builtin_amdgcn_mfma_f32_32x32x16_f16(kf[3], qf[3], s, 0,0,0);
    return s;
}

// finish: exp2 -> pack -> consistent-l via fdot2 -> PV. Same ops as R8/R11.
static __device__ __forceinline__ void finish_pv(const f32x16& S, float& lac,
                                                 f32x16& o0, f32x16& o1,
                                                 const f16x8 (&vf)[4]){
    f32x16 p;
#pragma unroll
    for(int r=0;r<16;++r) p[r] = __builtin_amdgcn_exp2f(S[r]);
    u32 A0 = pkf16(p[0],p[1]),   A1 = pkf16(p[2],p[3]);
    u32 B0 = pkf16(p[4],p[5]),   B1 = pkf16(p[6],p[7]);
    u32 C0 = pkf16(p[8],p[9]),   C1 = pkf16(p[10],p[11]);
    u32 D0 = pkf16(p[12],p[13]), D1 = pkf16(p[14],p[15]);
    u32x2 r0 = swp(A0,B0), r1 = swp(A1,B1);
    u32x2 r2 = swp(C0,D0), r3 = swp(C1,D1);
    u32x4 w0 = {r0.x, r1.x, r0.y, r1.y};   // keys [0,16) of this 32-key group
    u32x4 w1 = {r2.x, r3.x, r2.y, r3.y};   // keys [16,32)
    f16x8 pa0 = __builtin_bit_cast(f16x8, w0);
    f16x8 pa1 = __builtin_bit_cast(f16x8, w1);
    const f16x2 ones = {(_Float16)1.0f, (_Float16)1.0f};
#pragma unroll
    for(int j=0;j<4;++j){
        f16x2 c0 = {pa0[2*j], pa0[2*j+1]};
        f16x2 c1 = {pa1[2*j], pa1[2*j+1]};
        lac = __builtin_amdgcn_fdot2(c0, ones, lac, false);
        lac = __builtin_amdgcn_fdot2(c1, ones, lac, false);
    }
    o0 = __builtin_amdgcn_mfma_f32_32x32x16_f16(pa0, vf[0], o0, 0,0,0);
    o0 = __builtin_amdgcn_mfma_f32_32x32x16_f16(pa1, vf[2], o0, 0,0,0);
    o1 = __builtin_amdgcn_mfma_f32_32x32x16_f16(pa0, vf[1], o1, 0,0,0);
    o1 = __builtin_amdgcn_mfma_f32_32x32x16_f16(pa1, vf[3], o1, 0,0,0);
}

static __device__ __forceinline__ void ld4(f16x8 (&dst)[4], const char* base){
#pragma unroll
    for(int i=0;i<4;++i) dst[i] = *(const f16x8*)(base + (i<<10));
}

// ---- main kernel: 4-way KEY split with FULL R8 per-wave register state ----
// Allocator rule (R2..R14): VGPR ends up near the per-wave minimum live set,
// regardless of permitted occupancy. R13/R14 halved per-wave state (floor
// ~48) -> squeezed to 56-64 -> loads serialized -> slow despite 2x waves.
// THIS kernel keeps R8's state (o[2][2]=64 + qf[2][4]=32 -> floor ~112,
// squeeze-proof) and quarters the KEYS instead: wave (kh2,g) owns a 32-key
// group per mega-tile. 16 bh x 64 qblk x 4 kh = 4096 waves = 4 waves/SIMD
// at 4 x ~128 VGPR = the full 512-reg SIMD pool. Block = 4 waves sharing
// 64 queries; pairwise-tree epilogue in 32.5 KB LDS (caps 4 blocks/CU).
// Free-running main loop (no barriers) as R8/R11. Numerics: P and l
// identical; only final O-sum association changes (2-way -> 4-way tree).
__global__ __launch_bounds__(256,2)
void attn_fwd(const float* __restrict__ Qg, float* __restrict__ Og,
              const _Float16* __restrict__ kp, const _Float16* __restrict__ vp){
    __shared__ __align__(16) float xo[8320];   // 2x(64x64) bufs + 2x64 l = 32.5 KB

    const int tid  = threadIdx.x;
    const int lane = tid & 63, wv = tid >> 6;
    const int kh2 = wv >> 1, g = wv & 1;           // wave's 32-key quarter
    const int l31 = lane & 31, hi = lane >> 5;
    const int bh = blockIdx.x, b = bh>>3, h = bh&7;
    const int q0 = blockIdx.y*64;                  // block owns 64 queries

    const float c = 0.125f * 1.4426950408889634f;  // scale * log2(e)

    // Q B-frags (all 4 waves load the same 64 queries): lane=query l31
    f16x8 qf[2][4];
#pragma unroll
    for(int qt=0;qt<2;++qt){
        const float* qrow = Qg + (((size_t)b*Ln + q0 + qt*32 + l31)*Hn + h)*Dn;
#pragma unroll
        for(int cc=0;cc<4;++cc){
            const float* p4 = qrow + cc*16 + hi*8;
            float4 x = *(const float4*)p4;
            float4 y = *(const float4*)(p4+4);
            f16x8 f;
            f[0]=(_Float16)(x.x*c); f[1]=(_Float16)(x.y*c);
            f[2]=(_Float16)(x.z*c); f[3]=(_Float16)(x.w*c);
            f[4]=(_Float16)(y.x*c); f[5]=(_Float16)(y.y*c);
            f[6]=(_Float16)(y.z*c); f[7]=(_Float16)(y.w*c);
            qf[qt][cc]=f;
        }
    }

    f32x16 o[2][2];
    float lac[2] = {0.f, 0.f};
#pragma unroll
    for(int qt=0;qt<2;++qt)
#pragma unroll
        for(int dt=0;dt<2;++dt)
#pragma unroll
            for(int r=0;r<16;++r) o[qt][dt][r]=0.f;

    // wave's 32-key group inside each 16 KB mega-tile:
    // byte = kh2*8192 + g*4096 + unit*1024 + lane*16
    const int sub = kh2*8192 + g*4096 + lane*16;
    const char* kgc = (const char*)(kp + (size_t)bh*BH_STRIDE) + sub;
    const char* vgc = (const char*)(vp + (size_t)bh*BH_STRIDE) + sub;

    for(int T=0; T<NMEGA; ++T){
        const char* Kb = kgc + (size_t)T*16384;
        const char* Vb = vgc + (size_t)T*16384;

        f16x8 kf[4], vf[4];
        ld4(kf, Kb); ld4(vf, Vb);

        f32x16 S0 = qk4(kf, qf[0]);
        f32x16 S1 = qk4(kf, qf[1]);
        finish_pv(S0, lac[0], o[0][0], o[0][1], vf);
        finish_pv(S1, lac[1], o[1][0], o[1][1], vf);
    }

    // lane l and l^32 hold complementary 16-key halves of the group
    float lred[2];
#pragma unroll
    for(int qt=0;qt<2;++qt)
        lred[qt] = lac[qt] + __shfl_xor(lac[qt], 32, 64);

    // ---- epilogue: pairwise tree across the 4 waves ----
    float* xb0 = xo;            // 64x64
    float* xb1 = xo + 4096;     // 64x64
    float* xl0 = xo + 8192;     // 64
    float* xl1 = xo + 8256;     // 64

    // phase 1: g==1 waves publish
    if(g==1){
        float* xb = kh2 ? xb1 : xb0;
        float* xl = kh2 ? xl1 : xl0;
#pragma unroll
        for(int qt=0;qt<2;++qt){
#pragma unroll
            for(int dt=0;dt<2;++dt)
#pragma unroll
                for(int r=0;r<16;++r){
                    int qr = (r&3) + 8*(r>>2) + 4*hi;
                    xb[(qt*32 + qr)*64 + dt*32 + l31] = o[qt][dt][r];
                }
            if(hi==0) xl[qt*32 + l31] = lred[qt];
        }
    }
    __syncthreads();
    // phase 2: g==0 waves absorb their kh2 partner
    if(g==0){
        float* xb = kh2 ? xb1 : xb0;
        float* xl = kh2 ? xl1 : xl0;
#pragma unroll
        for(int qt=0;qt<2;++qt){
#pragma unroll
            for(int dt=0;dt<2;++dt)
#pragma unroll
                for(int r=0;r<16;++r){
                    int qr = (r&3) + 8*(r>>2) + 4*hi;
                    o[qt][dt][r] += xb[(qt*32 + qr)*64 + dt*32 + l31];
                }
            lred[qt] += xl[qt*32 + l31];
        }
    }
    __syncthreads();
    // phase 3: wave 2 (kh2=1,g=0) publishes its kh2=1 sum
    if(wv==2){
#pragma unroll
        for(int qt=0;qt<2;++qt){
#pragma unroll
            for(int dt=0;dt<2;++dt)
#pragma unroll
                for(int r=0;r<16;++r){
                    int qr = (r&3) + 8*(r>>2) + 4*hi;
                    xb0[(qt*32 + qr)*64 + dt*32 + l31] = o[qt][dt][r];
                }
            if(hi==0) xl0[qt*32 + l31] = lred[qt];
        }
    }
    __syncthreads();
    // phase 4: wave 0 finalizes and writes out
    if(wv==0){
#pragma unroll
        for(int qt=0;qt<2;++qt){
            float inv = 1.0f/(lred[qt] + xl0[qt*32 + l31]);
            float* ob = Og + (((size_t)b*Ln + q0 + qt*32)*Hn + h)*Dn;
#pragma unroll
            for(int r=0;r<16;++r){
                int qr = (r&3) + 8*(r>>2) + 4*hi;
                float invr = __shfl(inv, qr, 64);   // lane qr holds query qr's inv
                float v0 = o[qt][0][r] + xb0[(qt*32 + qr)*64 +  0 + l31];
                float v1 = o[qt][1][r] + xb0[(qt*32 + qr)*64 + 32 + l31];
                ob[(size_t)qr*Hn*Dn +  0 + l31] = v0*invr;
                ob[(size_t)qr*Hn*Dn + 32 + l31] = v1*invr;
            }
        }
    }
}

extern "C" void kernel_launch(void* const* d_in, const int* in_sizes, int n_in,
                              void* d_out, int out_size, void* d_ws, size_t ws_size,
                              hipStream_t stream) {
    const float* Q = (const float*)d_in[0];
    const float* K = (const float*)d_in[1];
    const float* V = (const float*)d_in[2];
    float* O = (float*)d_out;

    _Float16* kp = (_Float16*)d_ws;                        // 8 MB
    _Float16* vp = (_Float16*)((char*)d_ws + (8u<<20));    // 8 MB

    kvprep<<<dim3(128, 16), dim3(256), 0, stream>>>(K, V, kp, vp);
    attn_fwd<<<dim3(16, 64), dim3(256), 0, stream>>>(Q, O, kp, vp);
}